// Round 1
// baseline (257.927 us; speedup 1.0000x reference)
//
#include <hip/hip_runtime.h>
#include <hip/hip_bf16.h>

typedef __bf16 bf16x8 __attribute__((ext_vector_type(8)));
typedef float  f32x4  __attribute__((ext_vector_type(4)));

#define WBT_STRIDE 136   // bf16 elems per row, 80 rows x 128 k (pad -> 2-way banks)
#define H1_STRIDE  104   // bf16 elems per row, 16 rows x 96 k  (pad -> 2-way banks)
#define W3T_STRIDE 104   // bf16 elems per row, 48 rows x 96 k

__global__ __launch_bounds__(256, 2)
void attn_fcn_kernel(const float* __restrict__ query,
                     const float* __restrict__ facts,
                     const int*   __restrict__ mask,
                     const float* __restrict__ W1,
                     const float* __restrict__ b1,
                     const float* __restrict__ alpha,
                     const float* __restrict__ W2,
                     const float* __restrict__ b2,
                     const float* __restrict__ W3,
                     const float* __restrict__ b3,
                     const float* __restrict__ W4,
                     const float* __restrict__ b4,
                     float* __restrict__ out)
{
    __shared__ float  qy[128];
    __shared__ float  qs[128];
    __shared__ float  qconst[80];
    __shared__ __align__(16) __bf16 WbT[80 * WBT_STRIDE];      // folded W2 weight, transposed
    __shared__ __align__(16) __bf16 W3T[48 * W3T_STRIDE];      // W3 transposed, zero-padded
    __shared__ __align__(16) __bf16 h1sB[4][16 * H1_STRIDE];   // per-wave h1 tile (bf16)
    __shared__ float  sc16[4][16];
    __shared__ float  outacc[4][128];
    __shared__ float  MZ[4][2];
    __shared__ float  w4s[48];
    __shared__ float  b3s[48];

    const int b = blockIdx.x;
    const int t = threadIdx.x;

    // ---- Phase A0: stage query row; zero padded LDS regions ----
    if (t < 128) qy[t] = query[b * 128 + t];
    for (int e = t; e < 48 * W3T_STRIDE; e += 256) W3T[e] = (__bf16)0.0f;
    for (int e = t; e < 4 * 16 * H1_STRIDE; e += 256) (&h1sB[0][0])[e] = (__bf16)0.0f;
    if (t < 48) {
        w4s[t] = (t < 40) ? W4[t] : 0.0f;
        b3s[t] = (t < 40) ? b3[t] : 0.0f;
    }
    __syncthreads();

    // ---- Phase A1: fill W3T;  q = PReLU(query @ W1 + b1) ----
    for (int e = t; e < 80 * 40; e += 256) {
        int k = e / 40, j = e % 40;             // W3 row-major [80][40]
        W3T[j * W3T_STRIDE + k] = (__bf16)W3[e];
    }
    if (t < 128) {
        float acc = b1[t];
        #pragma unroll 4
        for (int k = 0; k < 128; ++k) acc = fmaf(qy[k], W1[k * 128 + t], acc);
        float a = alpha[t];
        qs[t] = (acc >= 0.0f) ? acc : a * acc;
    }
    __syncthreads();

    // ---- Phase B: qconst[j] = q@(W2a+W2c)+b2 ; WbT[n][k] = (W2b-W2c+q_k*W2d)[k][n] ----
    if (t < 80) {
        float acc = b2[t];
        #pragma unroll 4
        for (int k = 0; k < 128; ++k)
            acc = fmaf(qs[k], W2[k * 80 + t] + W2[(256 + k) * 80 + t], acc);
        qconst[t] = acc;
    }
    for (int e = t; e < 128 * 80; e += 256) {
        int k = e / 80, n = e % 80;
        float w = W2[(128 + k) * 80 + n] - W2[(256 + k) * 80 + n]
                + qs[k] * W2[(384 + k) * 80 + n];
        WbT[n * WBT_STRIDE + k] = (__bf16)w;
    }
    __syncthreads();

    // ---- Phase C: per-wave row-tiles of 16, fused GEMM1->GEMM2->score->online softmax ----
    const int wave = t >> 6;
    const int lane = t & 63;
    const int qd   = lane >> 4;   // quad 0..3
    const int m    = lane & 15;
    const float b4v = b4[0];
    const float* fb = facts + (size_t)b * (512 * 128);
    const int*   mb = mask + b * 512;
    __bf16* h1w = &h1sB[wave][0];

    // W3 B-fragments (K=96 padded, N=48 padded), register resident
    bf16x8 w3f[3][3];
    #pragma unroll
    for (int ct = 0; ct < 3; ++ct)
        #pragma unroll
        for (int kc = 0; kc < 3; ++kc)
            w3f[ct][kc] = *(const bf16x8*)&W3T[(ct * 16 + m) * W3T_STRIDE + kc * 32 + qd * 8];

    float Mrun = -INFINITY, Zrun = 0.0f;
    float oacc[4][8];
    #pragma unroll
    for (int kc = 0; kc < 4; ++kc)
        #pragma unroll
        for (int i = 0; i < 8; ++i) oacc[kc][i] = 0.0f;

    for (int tile = 0; tile < 8; ++tile) {
        const int s0 = wave * 128 + tile * 16;

        // fp32 facts slices: lane holds row s0+m, k = kc*32 + qd*8 + i
        f32x4 av[4][2];
        #pragma unroll
        for (int kc = 0; kc < 4; ++kc) {
            const float* p = &fb[(size_t)(s0 + m) * 128 + kc * 32 + qd * 8];
            av[kc][0] = *(const f32x4*)p;
            av[kc][1] = *(const f32x4*)(p + 4);
        }
        bf16x8 af[4];
        #pragma unroll
        for (int kc = 0; kc < 4; ++kc)
            #pragma unroll
            for (int i = 0; i < 8; ++i)
                af[kc][i] = (__bf16)((i < 4) ? av[kc][0][i] : av[kc][1][i - 4]);

        // GEMM1: [16,128] @ [128,80] -> sigmoid -> h1 (bf16, wave-private LDS)
        #pragma unroll
        for (int ct = 0; ct < 5; ++ct) {
            f32x4 acc = {0.f, 0.f, 0.f, 0.f};
            #pragma unroll
            for (int kc = 0; kc < 4; ++kc) {
                bf16x8 bfr = *(const bf16x8*)&WbT[(ct * 16 + m) * WBT_STRIDE + kc * 32 + qd * 8];
                acc = __builtin_amdgcn_mfma_f32_16x16x32_bf16(af[kc], bfr, acc, 0, 0, 0);
            }
            const int col = ct * 16 + m;             // C/D: col = lane&15, row = quad*4 + r
            const float qc = qconst[col];
            #pragma unroll
            for (int r = 0; r < 4; ++r) {
                float x = acc[r] + qc;
                float h = __builtin_amdgcn_rcpf(1.0f + __expf(-x));
                h1w[(qd * 4 + r) * H1_STRIDE + col] = (__bf16)h;
            }
        }
        asm volatile("s_waitcnt lgkmcnt(0)" ::: "memory");

        // GEMM2: [16,96] @ [96,48] -> sigmoid -> score = h2 @ W4
        bf16x8 a2[3];
        #pragma unroll
        for (int kc = 0; kc < 3; ++kc)
            a2[kc] = *(const bf16x8*)&h1w[m * H1_STRIDE + kc * 32 + qd * 8];
        float sc[4] = {0.f, 0.f, 0.f, 0.f};
        #pragma unroll
        for (int ct = 0; ct < 3; ++ct) {
            f32x4 acc2 = {0.f, 0.f, 0.f, 0.f};
            #pragma unroll
            for (int kc = 0; kc < 3; ++kc)
                acc2 = __builtin_amdgcn_mfma_f32_16x16x32_bf16(a2[kc], w3f[ct][kc], acc2, 0, 0, 0);
            const int col = ct * 16 + m;
            const float w4v = w4s[col], b3v = b3s[col];
            #pragma unroll
            for (int r = 0; r < 4; ++r) {
                float h2 = __builtin_amdgcn_rcpf(1.0f + __expf(-(acc2[r] + b3v)));
                sc[r] = fmaf(h2, w4v, sc[r]);
            }
        }
        #pragma unroll
        for (int d = 1; d < 16; d <<= 1)
            #pragma unroll
            for (int r = 0; r < 4; ++r)
                sc[r] += __shfl_xor(sc[r], d);
        if (m == 0) {
            #pragma unroll
            for (int r = 0; r < 4; ++r) {
                const int row = qd * 4 + r;
                float v = sc[r] + b4v;
                if (mb[s0 + row] != 1) v = -INFINITY;
                sc16[wave][row] = v;
            }
        }
        asm volatile("s_waitcnt lgkmcnt(0)" ::: "memory");

        // online softmax update (replicated across lanes; lane's own row is m)
        float tmax = -INFINITY;
        #pragma unroll
        for (int i = 0; i < 16; ++i) tmax = fmaxf(tmax, sc16[wave][i]);
        float Mn = fmaxf(Mrun, tmax);
        float alph, pm, tsum;
        if (Mn == -INFINITY) {         // whole prefix masked: keep zeros, avoid inf-inf NaN
            alph = 1.0f; pm = 0.0f; tsum = 0.0f;
        } else {
            alph = __expf(Mrun - Mn);  // Mrun=-inf -> 0
            tsum = 0.0f;
            #pragma unroll
            for (int i = 0; i < 16; ++i) tsum += __expf(sc16[wave][i] - Mn);
            pm = __expf(sc16[wave][m] - Mn);
        }
        Zrun = Zrun * alph + tsum;
        Mrun = Mn;
        #pragma unroll
        for (int kc = 0; kc < 4; ++kc) {
            #pragma unroll
            for (int i = 0; i < 4; ++i) {
                oacc[kc][i]     = fmaf(pm, av[kc][0][i], oacc[kc][i]     * alph);
                oacc[kc][i + 4] = fmaf(pm, av[kc][1][i], oacc[kc][i + 4] * alph);
            }
        }
    }

    // ---- Phase D: reduce over the 16 m-lanes; combine the 4 waves ----
    #pragma unroll
    for (int d = 1; d < 16; d <<= 1)
        #pragma unroll
        for (int kc = 0; kc < 4; ++kc)
            #pragma unroll
            for (int i = 0; i < 8; ++i)
                oacc[kc][i] += __shfl_xor(oacc[kc][i], d);
    if (m == 0) {
        #pragma unroll
        for (int kc = 0; kc < 4; ++kc)
            #pragma unroll
            for (int i = 0; i < 8; ++i)
                outacc[wave][kc * 32 + qd * 8 + i] = oacc[kc][i];
        if (lane == 0) { MZ[wave][0] = Mrun; MZ[wave][1] = Zrun; }
    }
    __syncthreads();

    if (t < 128) {
        float Mg = fmaxf(fmaxf(MZ[0][0], MZ[1][0]), fmaxf(MZ[2][0], MZ[3][0]));
        float Zg = 0.0f, val = 0.0f;
        #pragma unroll
        for (int w = 0; w < 4; ++w) {
            float swt = __expf(MZ[w][0] - Mg);
            Zg  = fmaf(MZ[w][1], swt, Zg);
            val = fmaf(outacc[w][t], swt, val);
        }
        out[b * 128 + t] = val / Zg;
    }
}

extern "C" void kernel_launch(void* const* d_in, const int* in_sizes, int n_in,
                              void* d_out, int out_size, void* d_ws, size_t ws_size,
                              hipStream_t stream) {
    (void)in_sizes; (void)n_in; (void)d_ws; (void)ws_size; (void)out_size;
    const float* query = (const float*)d_in[0];
    const float* facts = (const float*)d_in[1];
    const int*   mask  = (const int*)d_in[2];
    const float* W1 = (const float*)d_in[3];
    const float* b1 = (const float*)d_in[4];
    const float* al = (const float*)d_in[5];
    const float* W2 = (const float*)d_in[6];
    const float* b2 = (const float*)d_in[7];
    const float* W3 = (const float*)d_in[8];
    const float* b3 = (const float*)d_in[9];
    const float* W4 = (const float*)d_in[10];
    const float* b4 = (const float*)d_in[11];
    attn_fcn_kernel<<<dim3(512), dim3(256), 0, stream>>>(
        query, facts, mask, W1, b1, al, W2, b2, W3, b3, W4, b4, (float*)d_out);
}

// Round 2
// 256.653 us; speedup vs baseline: 1.0050x; 1.0050x over previous
//
#include <hip/hip_runtime.h>
#include <hip/hip_bf16.h>

typedef __bf16 bf16x8 __attribute__((ext_vector_type(8)));
typedef float  f32x4  __attribute__((ext_vector_type(4)));

#define WBT_STRIDE 136   // bf16/row, 80 rows x 128 k (272B row -> 2-way banks, free)
#define H1_STRIDE  104   // bf16/row, 16 rows x 96 k
#define W3T_STRIDE 104   // bf16/row, 48 rows x 96 k

__global__ __launch_bounds__(512, 4)
void attn_fcn_kernel(const float* __restrict__ query,
                     const float* __restrict__ facts,
                     const int*   __restrict__ mask,
                     const float* __restrict__ W1,
                     const float* __restrict__ b1,
                     const float* __restrict__ alpha,
                     const float* __restrict__ W2,
                     const float* __restrict__ b2,
                     const float* __restrict__ W3,
                     const float* __restrict__ b3,
                     const float* __restrict__ W4,
                     const float* __restrict__ b4,
                     float* __restrict__ out)
{
    __shared__ float  qy[128];
    __shared__ float  qs[128];
    __shared__ float  qconst[80];
    __shared__ float  w4s[48];
    __shared__ float  b3s[48];
    __shared__ __align__(16) __bf16 WbT[80 * WBT_STRIDE];     // folded W2, transposed
    __shared__ __align__(16) __bf16 W3T[48 * W3T_STRIDE];     // W3^T, zero-padded
    __shared__ __align__(16) __bf16 h1sB[8][16 * H1_STRIDE];  // per-wave h1 tile
    __shared__ float  scores[512];
    __shared__ float  wred[8];
    __shared__ float  wsum[8];
    __shared__ float  outacc[4][128];

    const int b = blockIdx.x;
    const int t = threadIdx.x;

    // ---- Phase A0: stage query; zero padded LDS ----
    if (t < 128) qy[t] = query[b * 128 + t];
    for (int e = t; e < 48 * W3T_STRIDE; e += 512) W3T[e] = (__bf16)0.0f;
    for (int e = t; e < 8 * 16 * H1_STRIDE; e += 512) (&h1sB[0][0])[e] = (__bf16)0.0f;
    if (t < 48) {
        w4s[t] = (t < 40) ? W4[t] : 0.0f;
        b3s[t] = (t < 40) ? b3[t] : 0.0f;
    }
    __syncthreads();

    // ---- Phase A1: W3T fill; q = PReLU(query @ W1 + b1) ----
    for (int e = t; e < 80 * 40; e += 512) {
        int k = e / 40, j = e % 40;           // W3 row-major [80][40]
        W3T[j * W3T_STRIDE + k] = (__bf16)W3[e];
    }
    if (t < 128) {
        float acc = b1[t];
        #pragma unroll 4
        for (int k = 0; k < 128; ++k) acc = fmaf(qy[k], W1[k * 128 + t], acc);
        float a = alpha[t];
        qs[t] = (acc >= 0.0f) ? acc : a * acc;
    }
    __syncthreads();

    // ---- Phase B: qconst = q@(W2a+W2c)+b2 ; WbT[n][k] = (W2b-W2c+q_k*W2d)[k][n] ----
    if (t < 80) {
        float acc = b2[t];
        #pragma unroll 4
        for (int k = 0; k < 128; ++k)
            acc = fmaf(qs[k], W2[k * 80 + t] + W2[(256 + k) * 80 + t], acc);
        qconst[t] = acc;
    }
    for (int e = t; e < 128 * 80; e += 512) {
        int k = e / 80, n = e % 80;
        float w = W2[(128 + k) * 80 + n] - W2[(256 + k) * 80 + n]
                + qs[k] * W2[(384 + k) * 80 + n];
        WbT[n * WBT_STRIDE + k] = (__bf16)w;
    }
    __syncthreads();

    // ---- Phase C: score computation. Wave w owns rows [64w, 64w+64), 4 tiles of 16 ----
    const int wave = t >> 6;
    const int lane = t & 63;
    const int qd   = lane >> 4;    // quad 0..3
    const int m    = lane & 15;
    const float* fb = facts + (size_t)b * (512 * 128);
    const int*   mb = mask + b * 512;
    __bf16* h1w = &h1sB[wave][0];
    const int wbase = wave * 64;

    // prefetch tile 0 facts rows (fp32); lane holds row wbase+m, k = kc*32+qd*8+i
    f32x4 av[4][2];
    {
        const float* p0 = &fb[(size_t)(wbase + m) * 128 + qd * 8];
        #pragma unroll
        for (int kc = 0; kc < 4; ++kc) {
            av[kc][0] = *(const f32x4*)(p0 + kc * 32);
            av[kc][1] = *(const f32x4*)(p0 + kc * 32 + 4);
        }
    }

    for (int tile = 0; tile < 4; ++tile) {
        const int s0 = wbase + tile * 16;

        bf16x8 af[4];
        #pragma unroll
        for (int kc = 0; kc < 4; ++kc)
            #pragma unroll
            for (int i = 0; i < 8; ++i)
                af[kc][i] = (__bf16)((i < 4) ? av[kc][0][i] : av[kc][1][i - 4]);

        if (tile < 3) {   // software prefetch next tile; in flight through both GEMMs
            const float* pn = &fb[(size_t)(s0 + 16 + m) * 128 + qd * 8];
            #pragma unroll
            for (int kc = 0; kc < 4; ++kc) {
                av[kc][0] = *(const f32x4*)(pn + kc * 32);
                av[kc][1] = *(const f32x4*)(pn + kc * 32 + 4);
            }
        }

        // GEMM1: [16,128] @ [128,80] -> sigmoid -> h1 (bf16, wave-private LDS)
        #pragma unroll
        for (int ct = 0; ct < 5; ++ct) {
            f32x4 acc = {0.f, 0.f, 0.f, 0.f};
            #pragma unroll
            for (int kc = 0; kc < 4; ++kc) {
                bf16x8 bfr = *(const bf16x8*)&WbT[(ct * 16 + m) * WBT_STRIDE + kc * 32 + qd * 8];
                acc = __builtin_amdgcn_mfma_f32_16x16x32_bf16(af[kc], bfr, acc, 0, 0, 0);
            }
            const int col = ct * 16 + m;          // C/D: col = lane&15, row = quad*4 + r
            const float qc = qconst[col];
            #pragma unroll
            for (int r = 0; r < 4; ++r) {
                float x = acc[r] + qc;
                float h = __builtin_amdgcn_rcpf(1.0f + __expf(-x));
                h1w[(qd * 4 + r) * H1_STRIDE + col] = (__bf16)h;
            }
        }
        asm volatile("s_waitcnt lgkmcnt(0)" ::: "memory");  // wave-private LDS: no barrier

        // GEMM2: [16,96] @ [96,48] -> sigmoid -> score = h2 @ W4
        bf16x8 a2[3];
        #pragma unroll
        for (int kc = 0; kc < 3; ++kc)
            a2[kc] = *(const bf16x8*)&h1w[m * H1_STRIDE + kc * 32 + qd * 8];
        float sc[4] = {0.f, 0.f, 0.f, 0.f};
        #pragma unroll
        for (int ct = 0; ct < 3; ++ct) {
            f32x4 acc2 = {0.f, 0.f, 0.f, 0.f};
            #pragma unroll
            for (int kc = 0; kc < 3; ++kc) {
                bf16x8 bfr = *(const bf16x8*)&W3T[(ct * 16 + m) * W3T_STRIDE + kc * 32 + qd * 8];
                acc2 = __builtin_amdgcn_mfma_f32_16x16x32_bf16(a2[kc], bfr, acc2, 0, 0, 0);
            }
            const int col = ct * 16 + m;
            const float w4v = w4s[col], b3v = b3s[col];
            #pragma unroll
            for (int r = 0; r < 4; ++r) {
                float h2 = __builtin_amdgcn_rcpf(1.0f + __expf(-(acc2[r] + b3v)));
                sc[r] = fmaf(h2, w4v, sc[r]);
            }
        }
        #pragma unroll
        for (int d = 1; d < 16; d <<= 1)
            #pragma unroll
            for (int r = 0; r < 4; ++r)
                sc[r] += __shfl_xor(sc[r], d);
        if (m == 0) {
            #pragma unroll
            for (int r = 0; r < 4; ++r)
                scores[s0 + qd * 4 + r] = sc[r];
        }
    }
    __syncthreads();

    // ---- Phase D: flat softmax over 512 scores ----
    const float b4v = b4[0];
    float v = scores[t] + b4v;
    if (mb[t] != 1) v = -INFINITY;
    float r = v;
    #pragma unroll
    for (int d = 1; d < 64; d <<= 1) r = fmaxf(r, __shfl_xor(r, d));
    if (lane == 0) wred[wave] = r;
    __syncthreads();
    float gmax = wred[0];
    #pragma unroll
    for (int w = 1; w < 8; ++w) gmax = fmaxf(gmax, wred[w]);
    float e = (gmax == -INFINITY) ? 1.0f : __expf(v - gmax);  // all-masked -> uniform
    float z = e;
    #pragma unroll
    for (int d = 1; d < 64; d <<= 1) z += __shfl_xor(z, d);
    if (lane == 0) wsum[wave] = z;
    scores[t] = e;           // unnormalized weight
    __syncthreads();
    float Zg = wsum[0];
    #pragma unroll
    for (int w = 1; w < 8; ++w) Zg += wsum[w];

    // ---- Phase E: out[f] = (1/Z) * sum_s e_s * facts[s][f] ----
    {
        const int f   = t & 127;
        const int qtr = t >> 7;             // 0..3, each owns 128 seq rows
        const float* fp = fb + (size_t)qtr * 128 * 128 + f;
        const float* pp = &scores[qtr * 128];
        float a0 = 0.f, a1 = 0.f, a2 = 0.f, a3 = 0.f;
        #pragma unroll 4
        for (int s = 0; s < 128; s += 4) {
            a0 = fmaf(pp[s],     fp[(size_t)(s)     * 128], a0);
            a1 = fmaf(pp[s + 1], fp[(size_t)(s + 1) * 128], a1);
            a2 = fmaf(pp[s + 2], fp[(size_t)(s + 2) * 128], a2);
            a3 = fmaf(pp[s + 3], fp[(size_t)(s + 3) * 128], a3);
        }
        outacc[qtr][f] = (a0 + a1) + (a2 + a3);
    }
    __syncthreads();
    if (t < 128)
        out[b * 128 + t] =
            ((outacc[0][t] + outacc[1][t]) + (outacc[2][t] + outacc[3][t])) / Zg;
}

extern "C" void kernel_launch(void* const* d_in, const int* in_sizes, int n_in,
                              void* d_out, int out_size, void* d_ws, size_t ws_size,
                              hipStream_t stream) {
    (void)in_sizes; (void)n_in; (void)d_ws; (void)ws_size; (void)out_size;
    const float* query = (const float*)d_in[0];
    const float* facts = (const float*)d_in[1];
    const int*   mask  = (const int*)d_in[2];
    const float* W1 = (const float*)d_in[3];
    const float* b1 = (const float*)d_in[4];
    const float* al = (const float*)d_in[5];
    const float* W2 = (const float*)d_in[6];
    const float* b2 = (const float*)d_in[7];
    const float* W3 = (const float*)d_in[8];
    const float* b3 = (const float*)d_in[9];
    const float* W4 = (const float*)d_in[10];
    const float* b4 = (const float*)d_in[11];
    attn_fcn_kernel<<<dim3(512), dim3(512), 0, stream>>>(
        query, facts, mask, W1, b1, al, W2, b2, W3, b3, W4, b4, (float*)d_out);
}

// Round 3
// 249.942 us; speedup vs baseline: 1.0319x; 1.0269x over previous
//
#include <hip/hip_runtime.h>
#include <hip/hip_bf16.h>

typedef __bf16 bf16x8 __attribute__((ext_vector_type(8)));
typedef float  f32x4  __attribute__((ext_vector_type(4)));

#define WBT_STRIDE 136   // LDS bf16/row: 80 rows x 128 k, 272B rows (16B aligned, 2-way banks)
#define H1_STRIDE  104   // LDS bf16/row: 16 rows x 96 k, 208B rows (16B aligned)

// workspace layout (bytes)
#define WS_WBT   0u             // bf16 [512][128][80]  (k-major folded W2)  10,485,760
#define WS_QC    10485760u      // f32  [512][80]                               163,840
#define WS_W3T   10649600u      // bf16 [48][96] zero-padded W3^T                 9,216
#define WS_OP    10658816u      // f32  [1024][128] partial outputs             524,288
#define WS_Z     11183104u      // f32  [1024]   partial Z                        4,096

// ---------------- K1: per-batch prep -----------------
__global__ __launch_bounds__(256)
void k1_prep(const float* __restrict__ query,
             const float* __restrict__ W1, const float* __restrict__ b1,
             const float* __restrict__ alpha,
             const float* __restrict__ W2, const float* __restrict__ b2,
             const float* __restrict__ W3,
             unsigned char* __restrict__ ws)
{
    __shared__ float qy[128];
    __shared__ float qpart[2][128];
    __shared__ float qs[128];
    __shared__ float qcp[2][80];

    const int b = blockIdx.x;
    const int t = threadIdx.x;
    __hip_bfloat16* wbt = (__hip_bfloat16*)(ws + WS_WBT);
    float*          qcw = (float*)(ws + WS_QC);
    __hip_bfloat16* w3t = (__hip_bfloat16*)(ws + WS_W3T);

    if (t < 128) qy[t] = query[b * 128 + t];
    __syncthreads();

    // q = query @ W1 + b1 (split-K x2)
    {
        const int j = t & 127, kh = t >> 7;
        float acc = (kh == 0) ? b1[j] : 0.0f;
        const float* w1p = W1 + (kh * 64) * 128 + j;
        #pragma unroll 4
        for (int k = 0; k < 64; ++k) acc = fmaf(qy[kh * 64 + k], w1p[k * 128], acc);
        qpart[kh][j] = acc;
    }
    // one-time W3^T zero-padded [48][96] (block 0 only)
    if (b == 0) {
        for (int e = t; e < 48 * 96; e += 256) {
            int j = e / 96, k = e % 96;
            float v = (j < 40 && k < 80) ? W3[k * 40 + j] : 0.0f;
            w3t[e] = __hip_bfloat16(v);
        }
    }
    __syncthreads();
    if (t < 128) {
        float s = qpart[0][t] + qpart[1][t];
        float a = alpha[t];
        qs[t] = (s >= 0.0f) ? s : a * s;
    }
    __syncthreads();

    // qconst[j] = q @ (W2a + W2c) + b2   (split-K x2, 160 threads)
    if (t < 160) {
        const int jj = (t < 80) ? t : t - 80;
        const int hh = (t < 80) ? 0 : 1;
        float acc = (hh == 0) ? b2[jj] : 0.0f;
        #pragma unroll 4
        for (int k = hh * 64; k < hh * 64 + 64; ++k)
            acc = fmaf(qs[k], W2[k * 80 + jj] + W2[(256 + k) * 80 + jj], acc);
        qcp[hh][jj] = acc;
    }
    // fold: wbt[b][k][n] = W2b - W2c + q_k * W2d   (coalesced in and out)
    for (int e = t; e < 128 * 80; e += 256) {
        int k = e / 80, n = e - k * 80;
        float w = W2[(128 + k) * 80 + n] - W2[(256 + k) * 80 + n]
                + qs[k] * W2[(384 + k) * 80 + n];
        wbt[b * 10240 + e] = __hip_bfloat16(w);
    }
    __syncthreads();
    if (t < 80) qcw[b * 80 + t] = qcp[0][t] + qcp[1][t];
}

// ---------------- K2: scores + exp + weighted partial sum -----------------
__global__ __launch_bounds__(256, 4)
void k2_main(const float* __restrict__ facts,
             const int*   __restrict__ mask,
             const float* __restrict__ W4, const float* __restrict__ b3,
             unsigned char* __restrict__ ws)
{
    __shared__ __align__(16) __bf16 WbT[80 * WBT_STRIDE];
    __shared__ __align__(16) __bf16 h1sB[4][16 * H1_STRIDE];
    __shared__ float qcs[80];
    __shared__ float w4s[48];
    __shared__ float b3s[48];
    __shared__ float sc16[4][16];
    __shared__ float outacc[4][128];
    __shared__ float Zw[4];

    const int b2 = blockIdx.x;
    const int batch = b2 >> 1;
    const int half  = b2 & 1;
    const int t = threadIdx.x;

    const __hip_bfloat16* wbt = (const __hip_bfloat16*)(ws + WS_WBT) + batch * 10240;
    const float*          qcw = (const float*)(ws + WS_QC) + batch * 80;
    const __bf16*         w3t = (const __bf16*)(ws + WS_W3T);
    float*                opw = (float*)(ws + WS_OP);
    float*                zpw = (float*)(ws + WS_Z);

    // stage WbT (transpose k-major ws -> [n][k] LDS), vectorized loads
    #pragma unroll
    for (int i = 0; i < 5; ++i) {
        int elem = (t + i * 256) * 8;           // 8 consecutive n within one k
        bf16x8 v = *(const bf16x8*)&wbt[elem];
        int k = elem / 80, n = elem - k * 80;
        #pragma unroll
        for (int j = 0; j < 8; ++j) WbT[(n + j) * WBT_STRIDE + k] = v[j];
    }
    // zero h1 cols 80..95 (once; GEMM2 pads K to 96 — W3T is zero there anyway,
    // but keep h1 finite to be safe)
    for (int e = t; e < 64 * 16; e += 256) {
        int r = e >> 4, c = 80 + (e & 15);
        (&h1sB[0][0])[r * H1_STRIDE + c] = (__bf16)0.0f;
    }
    if (t < 80) qcs[t] = qcw[t];
    if (t < 48) {
        w4s[t] = (t < 40) ? W4[t] : 0.0f;
        b3s[t] = (t < 40) ? b3[t] : 0.0f;
    }
    __syncthreads();

    const int wave = t >> 6;
    const int lane = t & 63;
    const int qd   = lane >> 4;
    const int m    = lane & 15;
    const float* fb = facts + (size_t)batch * (512 * 128);
    const int*   mb = mask + batch * 512;
    __bf16* h1w = &h1sB[wave][0];
    const int sbase = half * 256 + wave * 64;

    float oacc[4][8];
    #pragma unroll
    for (int kc = 0; kc < 4; ++kc)
        #pragma unroll
        for (int i = 0; i < 8; ++i) oacc[kc][i] = 0.0f;
    float Zl = 0.0f;

    for (int tile = 0; tile < 4; ++tile) {
        const int s0 = sbase + tile * 16;
        const int mv = mb[s0 + m];              // issue early with the row loads

        f32x4 av[4][2];
        {
            const float* p0 = &fb[(size_t)(s0 + m) * 128 + qd * 8];
            #pragma unroll
            for (int kc = 0; kc < 4; ++kc) {
                av[kc][0] = *(const f32x4*)(p0 + kc * 32);
                av[kc][1] = *(const f32x4*)(p0 + kc * 32 + 4);
            }
        }
        bf16x8 af[4];
        #pragma unroll
        for (int kc = 0; kc < 4; ++kc)
            #pragma unroll
            for (int i = 0; i < 8; ++i)
                af[kc][i] = (__bf16)((i < 4) ? av[kc][0][i] : av[kc][1][i - 4]);

        // GEMM1: [16,128] @ [128,80] -> sigmoid -> h1
        #pragma unroll
        for (int ct = 0; ct < 5; ++ct) {
            f32x4 acc = {0.f, 0.f, 0.f, 0.f};
            #pragma unroll
            for (int kc = 0; kc < 4; ++kc) {
                bf16x8 bfr = *(const bf16x8*)&WbT[(ct * 16 + m) * WBT_STRIDE + kc * 32 + qd * 8];
                acc = __builtin_amdgcn_mfma_f32_16x16x32_bf16(af[kc], bfr, acc, 0, 0, 0);
            }
            const int col = ct * 16 + m;
            const float qc = qcs[col];
            #pragma unroll
            for (int r = 0; r < 4; ++r) {
                float x = acc[r] + qc;
                float h = __builtin_amdgcn_rcpf(1.0f + __expf(-x));
                h1w[(qd * 4 + r) * H1_STRIDE + col] = (__bf16)h;
            }
        }
        asm volatile("s_waitcnt lgkmcnt(0)" ::: "memory");

        // GEMM2: [16,96] @ [96,48]; W3T fragments streamed from global (L2-hot)
        bf16x8 a2[3];
        #pragma unroll
        for (int kc = 0; kc < 3; ++kc)
            a2[kc] = *(const bf16x8*)&h1w[m * H1_STRIDE + kc * 32 + qd * 8];
        float sc[4] = {0.f, 0.f, 0.f, 0.f};
        #pragma unroll
        for (int ct = 0; ct < 3; ++ct) {
            f32x4 acc2 = {0.f, 0.f, 0.f, 0.f};
            #pragma unroll
            for (int kc = 0; kc < 3; ++kc) {
                bf16x8 bfr = *(const bf16x8*)&w3t[(ct * 16 + m) * 96 + kc * 32 + qd * 8];
                acc2 = __builtin_amdgcn_mfma_f32_16x16x32_bf16(a2[kc], bfr, acc2, 0, 0, 0);
            }
            const int col = ct * 16 + m;
            const float w4v = w4s[col], b3v = b3s[col];
            #pragma unroll
            for (int r = 0; r < 4; ++r) {
                float h2 = __builtin_amdgcn_rcpf(1.0f + __expf(-(acc2[r] + b3v)));
                sc[r] = fmaf(h2, w4v, sc[r]);
            }
        }
        #pragma unroll
        for (int d = 1; d < 16; d <<= 1)
            #pragma unroll
            for (int r = 0; r < 4; ++r)
                sc[r] += __shfl_xor(sc[r], d);
        if (m == 0) {
            #pragma unroll
            for (int r = 0; r < 4; ++r) sc16[wave][qd * 4 + r] = sc[r];
        }
        asm volatile("s_waitcnt lgkmcnt(0)" ::: "memory");

        // p = mask ? exp(score) : 0   (|score| <= sum|W4| ~ 5 -> no max-shift needed;
        //  b4 cancels under softmax)
        const float pm = (mv == 1) ? __expf(sc16[wave][m]) : 0.0f;
        Zl += pm;
        #pragma unroll
        for (int kc = 0; kc < 4; ++kc)
            #pragma unroll
            for (int i = 0; i < 4; ++i) {
                oacc[kc][i]     = fmaf(pm, av[kc][0][i], oacc[kc][i]);
                oacc[kc][i + 4] = fmaf(pm, av[kc][1][i], oacc[kc][i + 4]);
            }
    }

    // reduce over the 16 m-lanes
    #pragma unroll
    for (int d = 1; d < 16; d <<= 1) {
        #pragma unroll
        for (int kc = 0; kc < 4; ++kc)
            #pragma unroll
            for (int i = 0; i < 8; ++i)
                oacc[kc][i] += __shfl_xor(oacc[kc][i], d);
        Zl += __shfl_xor(Zl, d);
    }
    if (m == 0) {
        #pragma unroll
        for (int kc = 0; kc < 4; ++kc)
            #pragma unroll
            for (int i = 0; i < 8; ++i)
                outacc[wave][kc * 32 + qd * 8 + i] = oacc[kc][i];
        if (lane == 0) Zw[wave] = Zl;
    }
    __syncthreads();

    if (t < 128)
        opw[(size_t)b2 * 128 + t] =
            ((outacc[0][t] + outacc[1][t]) + (outacc[2][t] + outacc[3][t]));
    if (t == 0)
        zpw[b2] = (Zw[0] + Zw[1]) + (Zw[2] + Zw[3]);
}

// ---------------- K3: combine halves + normalize -----------------
__global__ __launch_bounds__(256)
void k3_combine(const unsigned char* __restrict__ ws, float* __restrict__ out)
{
    const float* opw = (const float*)(ws + WS_OP);
    const float* zpw = (const float*)(ws + WS_Z);
    int g = blockIdx.x * 256 + threadIdx.x;     // 65536 = 512*128
    int b = g >> 7, f = g & 127;
    float o = opw[(size_t)(2 * b) * 128 + f] + opw[(size_t)(2 * b + 1) * 128 + f];
    float Z = zpw[2 * b] + zpw[2 * b + 1];
    out[g] = o / Z;
}

extern "C" void kernel_launch(void* const* d_in, const int* in_sizes, int n_in,
                              void* d_out, int out_size, void* d_ws, size_t ws_size,
                              hipStream_t stream) {
    (void)in_sizes; (void)n_in; (void)ws_size; (void)out_size;
    const float* query = (const float*)d_in[0];
    const float* facts = (const float*)d_in[1];
    const int*   mask  = (const int*)d_in[2];
    const float* W1 = (const float*)d_in[3];
    const float* b1 = (const float*)d_in[4];
    const float* al = (const float*)d_in[5];
    const float* W2 = (const float*)d_in[6];
    const float* b2 = (const float*)d_in[7];
    const float* W3 = (const float*)d_in[8];
    const float* b3 = (const float*)d_in[9];
    const float* W4 = (const float*)d_in[10];
    const float* b4 = (const float*)d_in[11];
    (void)b4;  // cancels under softmax
    unsigned char* ws = (unsigned char*)d_ws;

    k1_prep<<<dim3(512), dim3(256), 0, stream>>>(query, W1, b1, al, W2, b2, W3, ws);
    k2_main<<<dim3(1024), dim3(256), 0, stream>>>(facts, mask, W4, b3, ws);
    k3_combine<<<dim3(256), dim3(256), 0, stream>>>(ws, (float*)d_out);
}

// Round 4
// 233.158 us; speedup vs baseline: 1.1062x; 1.0720x over previous
//
#include <hip/hip_runtime.h>
#include <hip/hip_bf16.h>

typedef __bf16 bf16x8 __attribute__((ext_vector_type(8)));
typedef float  f32x4  __attribute__((ext_vector_type(4)));

#define WBT_STRIDE 136   // bf16/row: 80 rows x 128 k; 272B rows (16B-aligned, 2-way banks)
#define H1_STRIDE  104   // bf16/row: 128 rows x 96 k; 208B rows
#define W3T_STRIDE 104   // bf16/row: 48 rows x 96 k

__global__ __launch_bounds__(512, 4)
void attn_fused(const float* __restrict__ query,
                const float* __restrict__ facts,
                const int*   __restrict__ mask,
                const float* __restrict__ W1, const float* __restrict__ b1,
                const float* __restrict__ alpha,
                const float* __restrict__ W2, const float* __restrict__ b2,
                const float* __restrict__ W3, const float* __restrict__ b3,
                const float* __restrict__ W4,
                float* __restrict__ out)
{
    __shared__ __align__(16) __bf16 WbT[80 * WBT_STRIDE];    // folded W2, [n][k]
    __shared__ __align__(16) __bf16 W3T[48 * W3T_STRIDE];    // W3^T zero-padded
    __shared__ __align__(16) __bf16 h1all[128 * H1_STRIDE];  // per-wave 16-row slabs
    __shared__ float qy[128], qs[128], qcs[80];
    __shared__ float qpart[4][128], qcp[4][80];
    __shared__ float w4s[48], b3s[48];
    __shared__ float outw[8 * 128];
    __shared__ float Zw[8];

    const int b = blockIdx.x, t = threadIdx.x;

    // ---- prologue: stage query, build W3^T, zero h1 pad cols, small vecs ----
    if (t < 128) qy[t] = query[b * 128 + t];
    for (int e = t; e < 48 * 96; e += 512) {
        int j = e / 96, k = e % 96;                          // W3 row-major [80][40]
        W3T[j * W3T_STRIDE + k] = (j < 40 && k < 80) ? (__bf16)W3[k * 40 + j]
                                                     : (__bf16)0.0f;
    }
    for (int e = t; e < 128 * 16; e += 512) {                // h1 cols 80..95 := 0
        int r = e >> 4, c = 80 + (e & 15);
        h1all[r * H1_STRIDE + c] = (__bf16)0.0f;
    }
    if (t < 48) { w4s[t] = (t < 40) ? W4[t] : 0.f; b3s[t] = (t < 40) ? b3[t] : 0.f; }
    __syncthreads();

    // q = PReLU(query @ W1 + b1), split-K x4
    {
        int j = t & 127, kh = t >> 7;
        float acc = (kh == 0) ? b1[j] : 0.f;
        const float* w1p = W1 + (kh * 32) * 128 + j;
        #pragma unroll 8
        for (int k = 0; k < 32; ++k) acc = fmaf(qy[kh * 32 + k], w1p[k * 128], acc);
        qpart[kh][j] = acc;
    }
    __syncthreads();
    if (t < 128) {
        float s = (qpart[0][t] + qpart[1][t]) + (qpart[2][t] + qpart[3][t]);
        qs[t] = (s >= 0.f) ? s : alpha[t] * s;
    }
    __syncthreads();

    // qconst = q@(W2a+W2c)+b2 (split-K x4); fold WbT[n][k] = W2b - W2c + q_k*W2d
    if (t < 320) {
        int jj = t % 80, hh = t / 80;
        float acc = (hh == 0) ? b2[jj] : 0.f;
        #pragma unroll 8
        for (int k = hh * 32; k < hh * 32 + 32; ++k)
            acc = fmaf(qs[k], W2[k * 80 + jj] + W2[(256 + k) * 80 + jj], acc);
        qcp[hh][jj] = acc;
    }
    for (int e = t; e < 128 * 80; e += 512) {
        int k = e / 80, n = e - k * 80;
        float w = W2[(128 + k) * 80 + n] - W2[(256 + k) * 80 + n]
                + qs[k] * W2[(384 + k) * 80 + n];
        WbT[n * WBT_STRIDE + k] = (__bf16)w;
    }
    __syncthreads();
    if (t < 80) qcs[t] = (qcp[0][t] + qcp[1][t]) + (qcp[2][t] + qcp[3][t]);
    __syncthreads();

    // ---- main: wave owns rows [64w, 64w+64), 4 tiles of 16 ----
    const int wave = t >> 6, lane = t & 63, qd = lane >> 4, m = lane & 15;
    const float* fb = facts + (size_t)b * (512 * 128);
    const int*   mb = mask + b * 512;
    __bf16* h1w = &h1all[wave * 16 * H1_STRIDE];

    float oacc[4][8];
    #pragma unroll
    for (int kc = 0; kc < 4; ++kc)
        #pragma unroll
        for (int i = 0; i < 8; ++i) oacc[kc][i] = 0.f;
    float Zl = 0.f;

    for (int tile = 0; tile < 4; ++tile) {
        const int s0 = wave * 64 + tile * 16;
        const int mv = mb[s0 + m];

        f32x4 av[4][2];
        {
            const float* p0 = &fb[(size_t)(s0 + m) * 128 + qd * 8];
            #pragma unroll
            for (int kc = 0; kc < 4; ++kc) {
                av[kc][0] = *(const f32x4*)(p0 + kc * 32);
                av[kc][1] = *(const f32x4*)(p0 + kc * 32 + 4);
            }
        }
        bf16x8 af[4];
        #pragma unroll
        for (int kc = 0; kc < 4; ++kc)
            #pragma unroll
            for (int i = 0; i < 8; ++i)
                af[kc][i] = (__bf16)((i < 4) ? av[kc][0][i] : av[kc][1][i - 4]);

        // GEMM1: [16,128]@[128,80] -> sigmoid -> h1 (wave-private LDS slab)
        #pragma unroll
        for (int ct = 0; ct < 5; ++ct) {
            f32x4 acc = {0.f, 0.f, 0.f, 0.f};
            #pragma unroll
            for (int kc = 0; kc < 4; ++kc) {
                bf16x8 bfr = *(const bf16x8*)&WbT[(ct * 16 + m) * WBT_STRIDE + kc * 32 + qd * 8];
                acc = __builtin_amdgcn_mfma_f32_16x16x32_bf16(af[kc], bfr, acc, 0, 0, 0);
            }
            const int col = ct * 16 + m;          // C/D: col = lane&15, row = quad*4+r
            const float qc = qcs[col];
            #pragma unroll
            for (int r = 0; r < 4; ++r) {
                float x = acc[r] + qc;
                float h = __builtin_amdgcn_rcpf(1.0f + __expf(-x));
                h1w[(qd * 4 + r) * H1_STRIDE + col] = (__bf16)h;
            }
        }
        asm volatile("s_waitcnt lgkmcnt(0)" ::: "memory");   // wave-private: no barrier

        // GEMM2: [16,96]@[96,48] -> sigmoid -> score = h2 @ W4
        bf16x8 a2[3];
        #pragma unroll
        for (int kc = 0; kc < 3; ++kc)
            a2[kc] = *(const bf16x8*)&h1w[m * H1_STRIDE + kc * 32 + qd * 8];
        float sc[4] = {0.f, 0.f, 0.f, 0.f};
        #pragma unroll
        for (int ct = 0; ct < 3; ++ct) {
            f32x4 acc2 = {0.f, 0.f, 0.f, 0.f};
            #pragma unroll
            for (int kc = 0; kc < 3; ++kc) {
                bf16x8 bfr = *(const bf16x8*)&W3T[(ct * 16 + m) * W3T_STRIDE + kc * 32 + qd * 8];
                acc2 = __builtin_amdgcn_mfma_f32_16x16x32_bf16(a2[kc], bfr, acc2, 0, 0, 0);
            }
            const int col = ct * 16 + m;
            const float w4v = w4s[col], b3v = b3s[col];
            #pragma unroll
            for (int r = 0; r < 4; ++r) {
                float h2 = __builtin_amdgcn_rcpf(1.0f + __expf(-(acc2[r] + b3v)));
                sc[r] = fmaf(h2, w4v, sc[r]);
            }
        }
        #pragma unroll
        for (int d = 1; d < 16; d <<= 1)
            #pragma unroll
            for (int r = 0; r < 4; ++r)
                sc[r] += __shfl_xor(sc[r], d);

        // own-row score via bpermute (row m lives as sc[m&3] in quad m>>2)
        const int idx = ((((m >> 2) << 4) | m) << 2);
        float s0v = __int_as_float(__builtin_amdgcn_ds_bpermute(idx, __float_as_int(sc[0])));
        float s1v = __int_as_float(__builtin_amdgcn_ds_bpermute(idx, __float_as_int(sc[1])));
        float s2v = __int_as_float(__builtin_amdgcn_ds_bpermute(idx, __float_as_int(sc[2])));
        float s3v = __int_as_float(__builtin_amdgcn_ds_bpermute(idx, __float_as_int(sc[3])));
        const int rr = m & 3;
        float srow = (rr == 0) ? s0v : (rr == 1) ? s1v : (rr == 2) ? s2v : s3v;

        // p = mask ? exp(score) : 0  (|score| <= sum|W4| ~ 5; b4 cancels in softmax)
        const float pm = (mv == 1) ? __expf(srow) : 0.f;
        Zl += pm;
        #pragma unroll
        for (int kc = 0; kc < 4; ++kc)
            #pragma unroll
            for (int i = 0; i < 4; ++i) {
                oacc[kc][i]     = fmaf(pm, av[kc][0][i], oacc[kc][i]);
                oacc[kc][i + 4] = fmaf(pm, av[kc][1][i], oacc[kc][i + 4]);
            }
    }

    // ---- epilogue: reduce over m, combine 8 waves, normalize ----
    #pragma unroll
    for (int d = 1; d < 16; d <<= 1) {
        #pragma unroll
        for (int kc = 0; kc < 4; ++kc)
            #pragma unroll
            for (int i = 0; i < 8; ++i)
                oacc[kc][i] += __shfl_xor(oacc[kc][i], d);
        Zl += __shfl_xor(Zl, d);
    }
    if (m == 0) {
        #pragma unroll
        for (int kc = 0; kc < 4; ++kc)
            #pragma unroll
            for (int i = 0; i < 8; ++i)
                outw[wave * 128 + kc * 32 + qd * 8 + i] = oacc[kc][i];
        if (lane == 0) Zw[wave] = Zl;
    }
    __syncthreads();

    if (t < 128) {
        float v = 0.f, Z = 0.f;
        #pragma unroll
        for (int w = 0; w < 8; ++w) { v += outw[w * 128 + t]; Z += Zw[w]; }
        out[b * 128 + t] = v / Z;
    }
}

extern "C" void kernel_launch(void* const* d_in, const int* in_sizes, int n_in,
                              void* d_out, int out_size, void* d_ws, size_t ws_size,
                              hipStream_t stream) {
    (void)in_sizes; (void)n_in; (void)d_ws; (void)ws_size; (void)out_size;
    const float* query = (const float*)d_in[0];
    const float* facts = (const float*)d_in[1];
    const int*   mask  = (const int*)d_in[2];
    const float* W1 = (const float*)d_in[3];
    const float* b1 = (const float*)d_in[4];
    const float* al = (const float*)d_in[5];
    const float* W2 = (const float*)d_in[6];
    const float* b2 = (const float*)d_in[7];
    const float* W3 = (const float*)d_in[8];
    const float* b3 = (const float*)d_in[9];
    const float* W4 = (const float*)d_in[10];
    const float* b4 = (const float*)d_in[11];
    (void)b4;  // cancels under softmax
    attn_fused<<<dim3(512), dim3(512), 0, stream>>>(
        query, facts, mask, W1, b1, al, W2, b2, W3, b3, W4, (float*)d_out);
}